// Round 13
// baseline (419.260 us; speedup 1.0000x reference)
//
#include <hip/hip_runtime.h>
#include <math.h>

#define NNODES 50000
#define NEG_SLOPE 0.2f
#define NBUCKET 391          // buckets of 128 nodes; s fits 16 bits (N < 65536)
#define NBIN_MAX 128

typedef unsigned short ushort8v __attribute__((ext_vector_type(8)));
typedef unsigned short ushort4v __attribute__((ext_vector_type(4)));
typedef short short8v __attribute__((ext_vector_type(8)));
typedef float f32x4 __attribute__((ext_vector_type(4)));
typedef float f32x2 __attribute__((ext_vector_type(2)));

__device__ __forceinline__ unsigned short f2bf(float f){
    unsigned u = __float_as_uint(f);
    u += 0x7fff + ((u >> 16) & 1);   // RNE; inputs finite
    return (unsigned short)(u >> 16);
}

// ---------------- prep helpers ----------------
__device__ __forceinline__ void emit_wa(const float* __restrict__ W, const float* __restrict__ a_s,
                                        const float* __restrict__ a_d, unsigned short* __restrict__ Wt,
                                        int Kin, int C, int id){
    const int n = id / Kin, k = id - n * Kin;
    float v = 0.f;
    if(n < 8){
        const int hh = n & 3;
        const float* av = (n < 4) ? a_s : a_d;
        for(int c = 0; c < C; c++) v += W[(size_t)k * (4 * C) + hh * C + c] * av[hh * C + c];
    }
    Wt[id] = f2bf(v);
}

__device__ __forceinline__ void emit_wc(const float* __restrict__ W, unsigned short* __restrict__ Wt,
                                        int Kin, int C, int id){
    const int c = id / (4 * Kin);
    const int hk = id - c * (4 * Kin);
    const int h = hk / Kin, k = hk - h * Kin;
    const float v = (c < C) ? W[(size_t)k * (4 * C) + h * C + c] * 0.25f : 0.f;
    Wt[id] = f2bf(v);
}

// ---------------- dispatch 1: prep ∪ bincount ----------------
// Blocks [0, prepBlocks): flag detect (block 0) + xbf + Wa* + Wc*.
// Blocks [prepBlocks, prepBlocks+64): per-block LDS bucket histogram of a 1/64 edge
// chunk; flag recomputed locally via per-wave ballot (no cross-block dependency).
__global__ __launch_bounds__(256) void prep_hist_kernel(
        const unsigned long long* __restrict__ e, int* __restrict__ flag,
        const float* __restrict__ x, unsigned short* __restrict__ xbf, int X4,
        const float* __restrict__ W1, const float* __restrict__ as1, const float* __restrict__ ad1,
        const float* __restrict__ W2, const float* __restrict__ as2, const float* __restrict__ ad2,
        const float* __restrict__ W3, const float* __restrict__ as3, const float* __restrict__ ad3,
        unsigned short* __restrict__ Wa1, unsigned short* __restrict__ Wa2,
        unsigned short* __restrict__ Wa3, unsigned short* __restrict__ Wc1,
        unsigned short* __restrict__ Wc2, unsigned short* __restrict__ Wc3,
        int* __restrict__ blkcnt,
        int E, int nbin, int chunk, int prepBlocks){
    __shared__ int lcnt[NBUCKET];
    const int t = threadIdx.x;

    if((int)blockIdx.x < prepBlocks){
        if(blockIdx.x == 0 && t < 64){
            const unsigned long long v = e[t];
            const unsigned long long mask = __ballot(v >= (1ULL << 32));
            if(t == 0) *flag = (mask == 0ULL) ? 1 : 0;
        }
        int id = blockIdx.x * 256 + t;
        if(id < X4){
            const float4 v = *(const float4*)&x[(size_t)id * 4];
            ushort4v o;
            o[0] = f2bf(v.x); o[1] = f2bf(v.y); o[2] = f2bf(v.z); o[3] = f2bf(v.w);
            *(ushort4v*)&xbf[(size_t)id * 4] = o;
            return;
        }
        id -= X4;
        if(id < 16 * 128){ emit_wa(W1, as1, ad1, Wa1, 128, 64, id); return; }
        id -= 16 * 128;
        if(id < 16 * 64){ emit_wa(W2, as2, ad2, Wa2, 64, 64, id); return; }
        id -= 16 * 64;
        if(id < 16 * 64){ emit_wa(W3, as3, ad3, Wa3, 64, 40, id); return; }
        id -= 16 * 64;
        if(id < 64 * 512){ emit_wc(W1, Wc1, 128, 64, id); return; }
        id -= 64 * 512;
        if(id < 64 * 256){ emit_wc(W2, Wc2, 64, 64, id); return; }
        id -= 64 * 256;
        if(id < 48 * 256){ emit_wc(W3, Wc3, 64, 40, id); }
        return;
    }

    // ---- bincount block ----
    const int bb = blockIdx.x - prepBlocks;       // 0..63
    for(int i = t; i < NBUCKET; i += 256) lcnt[i] = 0;
    // local flag: lanes of each wave read e[0..63], per-wave ballot (block-uniform)
    const unsigned long long v = e[t & 63];
    const unsigned long long mask = __ballot(v >= (1ULL << 32));
    const bool f = (mask == 0ULL);
    __syncthreads();
    const int beg = bb * chunk, end = min(beg + chunk, E);
    for(int i = beg + t; i < end; i += 256){
        const int d = f ? (int)((const long long*)e)[E + i] : ((const int*)e)[E + i];
        atomicAdd(&lcnt[d >> 7], 1);              // LDS atomic only
    }
    __syncthreads();
    for(int b = t; b < NBUCKET; b += 256) blkcnt[b * nbin + bb] = lcnt[b];
}

// ---------------- in-place exclusive scan of blkcnt[0..total) (single block) ----------
__global__ __launch_bounds__(256) void binscan_kernel(int* __restrict__ blkcnt, int total){
    __shared__ int part[256];
    const int t = threadIdx.x;
    const int per = (total + 255) / 256;
    const int beg = t * per, end = min(beg + per, total);
    int sum = 0;
    for(int i = beg; i < end; i++) sum += blkcnt[i];
    part[t] = sum;
    __syncthreads();
    for(int off = 1; off < 256; off <<= 1){
        const int add = (t >= off) ? part[t - off] : 0;
        __syncthreads();
        part[t] += add;
        __syncthreads();
    }
    int run = part[t] - sum;
    for(int i = beg; i < end; i++){
        const int v = blkcnt[i];
        blkcnt[i] = run;
        run += v;
    }
}

// ---------------- dispatch 3: binscatter ∪ agemm (layer-1 alpha) ----------------
__global__ __launch_bounds__(256) void scat_agemm_kernel(
        const void* __restrict__ e, const int* __restrict__ flag,
        const int* __restrict__ blkcnt, unsigned* __restrict__ ebuf,
        int E, int nbin, int chunk,
        const unsigned short* __restrict__ A, const unsigned short* __restrict__ Wa,
        float* __restrict__ ea, float* __restrict__ ed, int M){
    __shared__ int lcur[NBUCKET];
    const int t = threadIdx.x;
    if((int)blockIdx.x < 64){
        const int blk = blockIdx.x;
        for(int b = t; b < NBUCKET; b += 256) lcur[b] = blkcnt[b * nbin + blk];
        __syncthreads();
        const bool f = (*flag) != 0;
        const int beg = blk * chunk;
        const int end = min(beg + chunk, E);
        for(int i = beg + t; i < end; i += 256){
            int s, d;
            if(f){ s = (int)((const long long*)e)[i]; d = (int)((const long long*)e)[E + i]; }
            else { s = ((const int*)e)[i];            d = ((const int*)e)[E + i]; }
            const int b = d >> 7;
            const int p = atomicAdd(&lcur[b], 1);
            ebuf[p] = (unsigned)s | ((unsigned)(d & 127) << 16) | ((unsigned)b << 23);
        }
        return;
    }
    // ---- agemm<128> block ----
    constexpr int K = 128;
    const int lane = t & 63;
    const int wave = t >> 6;
    const int quad = lane >> 4;
    const int l16 = lane & 15;
    const int bm = ((int)blockIdx.x - 64) * 64;
    const int m = min(bm + wave * 16 + l16, M - 1);
    f32x4 acc = {0,0,0,0};
    #pragma unroll
    for(int k0 = 0; k0 < K; k0 += 32){
        const short8v a = *(const short8v*)&A[(size_t)m * K + k0 + quad * 8];
        const short8v b = *(const short8v*)&Wa[(size_t)l16 * K + k0 + quad * 8];
        acc = __builtin_amdgcn_mfma_f32_16x16x32_bf16(a, b, acc, 0, 0, 0);
    }
    if(l16 < 8){
        const int h = l16 & 3;
        float* dst = (l16 < 4) ? ea : ed;
        const int rbase = bm + wave * 16 + quad * 4;
        #pragma unroll
        for(int r = 0; r < 4; r++){
            const int row = rbase + r;
            if(row < M){
                const float v = acc[r];
                *(f32x2*)&dst[(size_t)row * 8 + 2 * h] = (f32x2){__expf(v), __expf(NEG_SLOPE * v)};
            }
        }
    }
}

// ---------------- per-bucket finalize: local hist + scan -> row_ptr; local scatter -> col
__global__ __launch_bounds__(256) void bfinal_kernel(const unsigned* __restrict__ ebuf,
                                                     const int* __restrict__ blkcnt,
                                                     int* __restrict__ row_ptr, int* __restrict__ col,
                                                     int N, int E, int nbin){
    __shared__ int lcnt[128], lcur[128], sh[128];
    const int b = blockIdx.x;
    const int t = threadIdx.x;
    const int nlo = b << 7;
    const int base = blkcnt[b * nbin];
    const int next = (b == NBUCKET - 1) ? E : blkcnt[(b + 1) * nbin];
    const int cnt = next - base;
    if(t < 128) lcnt[t] = 0;
    __syncthreads();
    for(int i = t; i < cnt; i += 256) atomicAdd(&lcnt[(ebuf[base + i] >> 16) & 127], 1);
    __syncthreads();
    if(t < 128) sh[t] = lcnt[t];
    __syncthreads();
    for(int off = 1; off < 128; off <<= 1){
        const int add = (t >= off && t < 128) ? sh[t - off] : 0;
        __syncthreads();
        if(t < 128) sh[t] += add;
        __syncthreads();
    }
    if(t < 128){
        const int excl = sh[t] - lcnt[t];
        lcur[t] = excl;
        if(nlo + t < N) row_ptr[nlo + t] = base + excl;
    }
    if(b == 0 && t == 0) row_ptr[N] = E;
    __syncthreads();
    for(int i = t; i < cnt; i += 256){
        const unsigned w = ebuf[base + i];
        const int p = atomicAdd(&lcur[(w >> 16) & 127], 1);
        col[base + p] = (int)(w & 0xffffu);
    }
}

// ---------------- edge-parallel RAW gather (round-11 shape; 8-deep edge unroll) ------
// g[n][h][K] = (sum_e w_h * X[s]) / dnm_h. Block 256 = 4 waves, 1 node/wave,
// 12500 dynamic blocks (HW dispatcher load-balances; static persistent grids
// regressed -- round 12). The per-edge X-row load is the latency bottleneck
// (~900cy HBM-miss); unrolling 8 independent body calls keeps 8 loads in
// flight (was 4) to halve exposed latency. Epilogue unchanged (round-9 lesson:
// epilogue shuffle tax must not grow).
template<int K>
__global__ __launch_bounds__(256) void gatherg_kernel(const unsigned short* __restrict__ X,
                                                      const int* __restrict__ row_ptr,
                                                      const int* __restrict__ col,
                                                      const float* __restrict__ ea,
                                                      const float* __restrict__ ed,
                                                      unsigned short* __restrict__ g){
    __shared__ int   ls[4][64];
    __shared__ float lw[4][64][4];
    const int lane = threadIdx.x & 63;
    const int wave = threadIdx.x >> 6;
    const int n    = blockIdx.x * 4 + wave;
    const int rs = row_ptr[n], re = row_ptr[n + 1];
    const int T = re - rs + 1;                    // edges + virtual self loop
    const float4 edA = *(const float4*)&ed[(size_t)n * 8];
    const float4 edB = *(const float4*)&ed[(size_t)n * 8 + 4];

    f32x2 acc[4];
    #pragma unroll
    for(int h = 0; h < 4; h++) acc[h] = (f32x2){0.f, 0.f};
    float d0 = 0.f, d1 = 0.f, d2 = 0.f, d3 = 0.f;

    const int c2 = (K == 128) ? (lane * 2) : ((lane & 31) * 2);
    const int eo = lane >> 5;

    for(int base = 0; base < T; base += 64){
        const int ecnt = min(T - base, 64);
        if(lane < ecnt){
            const int e = rs + base + lane;
            const int s = (e < re) ? col[e] : n;  // e==re => self loop
            const float4 eaA = *(const float4*)&ea[(size_t)s * 8];
            const float4 eaB = *(const float4*)&ea[(size_t)s * 8 + 4];
            const float w0 = fmaxf(eaA.x * edA.x, eaA.y * edA.y);
            const float w1 = fmaxf(eaA.z * edA.z, eaA.w * edA.w);
            const float w2 = fmaxf(eaB.x * edB.x, eaB.y * edB.y);
            const float w3 = fmaxf(eaB.z * edB.z, eaB.w * edB.w);
            d0 += w0; d1 += w1; d2 += w2; d3 += w3;
            ls[wave][lane] = s;
            *(f32x4*)&lw[wave][lane][0] = (f32x4){w0, w1, w2, w3};
        }
        if constexpr(K == 128){
            auto body = [&](int e){
                const int s = ls[wave][e];                      // LDS broadcast
                const f32x4 w4 = *(const f32x4*)&lw[wave][e][0];
                const unsigned u = *(const unsigned*)&X[(size_t)s * K + c2];
                const f32x2 v = {__uint_as_float(u << 16), __uint_as_float(u & 0xffff0000u)};
                acc[0] += (f32x2){w4[0], w4[0]} * v;
                acc[1] += (f32x2){w4[1], w4[1]} * v;
                acc[2] += (f32x2){w4[2], w4[2]} * v;
                acc[3] += (f32x2){w4[3], w4[3]} * v;
            };
            int e = 0;
            for(; e + 8 <= ecnt; e += 8){
                body(e);     body(e + 1); body(e + 2); body(e + 3);
                body(e + 4); body(e + 5); body(e + 6); body(e + 7);
            }
            for(; e + 4 <= ecnt; e += 4){ body(e); body(e + 1); body(e + 2); body(e + 3); }
            for(; e < ecnt; e++) body(e);
        } else {
            auto body = [&](int p){                             // pair: edges p, p+1
                const int e = p + eo;
                if(e < ecnt){
                    const int s = ls[wave][e];                  // 2-way LDS (free)
                    const f32x4 w4 = *(const f32x4*)&lw[wave][e][0];
                    const unsigned u = *(const unsigned*)&X[(size_t)s * K + c2];
                    const f32x2 v = {__uint_as_float(u << 16), __uint_as_float(u & 0xffff0000u)};
                    acc[0] += (f32x2){w4[0], w4[0]} * v;
                    acc[1] += (f32x2){w4[1], w4[1]} * v;
                    acc[2] += (f32x2){w4[2], w4[2]} * v;
                    acc[3] += (f32x2){w4[3], w4[3]} * v;
                }
            };
            int p = 0;
            for(; p + 16 <= ecnt; p += 16){
                body(p);      body(p + 2);  body(p + 4);  body(p + 6);
                body(p + 8);  body(p + 10); body(p + 12); body(p + 14);
            }
            for(; p + 8 <= ecnt; p += 8){ body(p); body(p + 2); body(p + 4); body(p + 6); }
            for(; p < ecnt; p += 2) body(p);
        }
    }

    #pragma unroll
    for(int msk = 1; msk < 64; msk <<= 1){
        d0 += __shfl_xor(d0, msk); d1 += __shfl_xor(d1, msk);
        d2 += __shfl_xor(d2, msk); d3 += __shfl_xor(d3, msk);
    }
    if constexpr(K == 64){
        #pragma unroll
        for(int h = 0; h < 4; h++){
            acc[h][0] += __shfl_xor(acc[h][0], 32);
            acc[h][1] += __shfl_xor(acc[h][1], 32);
        }
    }
    const float invs[4] = {1.f / d0, 1.f / d1, 1.f / d2, 1.f / d3};
    if(K == 128 || lane < 32){
        #pragma unroll
        for(int h = 0; h < 4; h++){
            const unsigned lo = f2bf(acc[h][0] * invs[h]);
            const unsigned hi = f2bf(acc[h][1] * invs[h]);
            *(unsigned*)&g[(size_t)n * (4 * K) + h * K + c2] = lo | (hi << 16);
        }
    }
}

// ---------------- post-aggregation GEMM (+fused next-layer alpha) ----------------
template<int KC, int NC, bool FINAL, bool ALPHA>
__global__ __launch_bounds__(256) void pgemm_kernel(const unsigned short* __restrict__ A,
                                                    const unsigned short* __restrict__ Bt,
                                                    const float* __restrict__ bias,
                                                    void* __restrict__ outv,
                                                    const unsigned short* __restrict__ Wa,
                                                    float* __restrict__ ea,
                                                    float* __restrict__ ed,
                                                    int M){
    constexpr int NT = (NC + 15) / 16;   // 4 (NC=64) or 3 (NC=40)
    __shared__ unsigned short lh[ALPHA ? 4 : 1][16][72];   // 72-stride: 16B-aligned rows, 2-way banks
    const int lane = threadIdx.x & 63;
    const int wave = threadIdx.x >> 6;
    const int quad = lane >> 4;
    const int l16 = lane & 15;
    const int bm = blockIdx.x * 64;
    const int m = min(bm + wave * 16 + l16, M - 1);
    const size_t arow = (size_t)m * KC;

    f32x4 acc[NT];
    #pragma unroll
    for(int t = 0; t < NT; t++) acc[t] = (f32x4){0,0,0,0};

    for(int k0 = 0; k0 < KC; k0 += 32){
        const short8v a = *(const short8v*)&A[arow + k0 + quad * 8];
        #pragma unroll
        for(int t = 0; t < NT; t++){
            const short8v b = *(const short8v*)&Bt[(size_t)(t * 16 + l16) * KC + k0 + quad * 8];
            acc[t] = __builtin_amdgcn_mfma_f32_16x16x32_bf16(a, b, acc[t], 0, 0, 0);
        }
    }
    const int rbase = bm + wave * 16 + quad * 4;
    if(!FINAL){
        unsigned short* out = (unsigned short*)outv;
        #pragma unroll
        for(int t = 0; t < NT; t++){
            const int c = t * 16 + l16;
            #pragma unroll
            for(int r = 0; r < 4; r++){
                const unsigned short hb = f2bf(fmaxf(acc[t][r] + bias[c], 0.f));
                const int row = rbase + r;
                if(row < M) out[(size_t)row * NC + c] = hb;
                if constexpr(ALPHA) lh[wave][quad * 4 + r][c] = hb;
            }
        }
        if constexpr(ALPHA){
            // wave-private LDS tile: within-wave lgkmcnt ordering suffices (no barrier)
            f32x4 a4 = {0, 0, 0, 0};
            #pragma unroll
            for(int k0 = 0; k0 < 64; k0 += 32){
                const short8v a = *(const short8v*)&lh[wave][l16][k0 + quad * 8];
                const short8v b = *(const short8v*)&Wa[(size_t)l16 * 64 + k0 + quad * 8];
                a4 = __builtin_amdgcn_mfma_f32_16x16x32_bf16(a, b, a4, 0, 0, 0);
            }
            if(l16 < 8){
                const int h = l16 & 3;
                float* dst = (l16 < 4) ? ea : ed;
                #pragma unroll
                for(int r = 0; r < 4; r++){
                    const int row = rbase + r;
                    if(row < M){
                        const float v = a4[r];
                        *(f32x2*)&dst[(size_t)row * 8 + 2 * h] = (f32x2){__expf(v), __expf(NEG_SLOPE * v)};
                    }
                }
            }
        }
    } else {
        float* out = (float*)outv;
        float o[NT][4];
        #pragma unroll
        for(int t = 0; t < NT; t++){
            const int c = t * 16 + l16;
            const bool valid = c < 40;
            const float bc = valid ? bias[c] : 0.f;
            #pragma unroll
            for(int r = 0; r < 4; r++)
                o[t][r] = valid ? fmaxf(acc[t][r] + bc, 0.f) : -INFINITY;
        }
        #pragma unroll
        for(int r = 0; r < 4; r++){
            float mx = o[0][r];
            #pragma unroll
            for(int t = 1; t < NT; t++) mx = fmaxf(mx, o[t][r]);
            #pragma unroll
            for(int off = 1; off < 16; off <<= 1) mx = fmaxf(mx, __shfl_xor(mx, off));
            float se = 0.f;
            #pragma unroll
            for(int t = 0; t < NT; t++) se += (o[t][r] > -INFINITY) ? __expf(o[t][r] - mx) : 0.f;
            #pragma unroll
            for(int off = 1; off < 16; off <<= 1) se += __shfl_xor(se, off);
            const float lz = mx + logf(se);
            const int row = rbase + r;
            if(row < M){
                #pragma unroll
                for(int t = 0; t < NT; t++){
                    const int c = t * 16 + l16;
                    if(c < 40) out[(size_t)row * 40 + c] = o[t][r] - lz;
                }
            }
        }
    }
}

// ---------------- driver ----------------
extern "C" void kernel_launch(void* const* d_in, const int* in_sizes, int n_in,
                              void* d_out, int out_size, void* d_ws, size_t ws_size,
                              hipStream_t stream){
    const int N = NNODES;
    const int E = in_sizes[1] / 2;

    const float* x   = (const float*)d_in[0];
    const float* W1  = (const float*)d_in[2];
    const float* as1 = (const float*)d_in[3];
    const float* ad1 = (const float*)d_in[4];
    const float* b1  = (const float*)d_in[5];
    const float* W2  = (const float*)d_in[6];
    const float* as2 = (const float*)d_in[7];
    const float* ad2 = (const float*)d_in[8];
    const float* b2  = (const float*)d_in[9];
    const float* W3  = (const float*)d_in[10];
    const float* as3 = (const float*)d_in[11];
    const float* ad3 = (const float*)d_in[12];
    const float* b3  = (const float*)d_in[13];

    char* ws = (char*)d_ws;
    size_t off = 0;
    auto alloc = [&](size_t bytes) -> void* {
        void* p = ws + off;
        off = (off + bytes + 255) & ~(size_t)255;
        return p;
    };
    int*      flag    = (int*)     alloc(4);
    int*      row_ptr = (int*)     alloc((size_t)(N + 1) * 4);
    int*      colv    = (int*)     alloc((size_t)E * 4);
    int*      blkcnt  = (int*)     alloc((size_t)NBUCKET * NBIN_MAX * 4);
    unsigned* ebuf    = (unsigned*)alloc((size_t)E * 4);
    unsigned short* xbf = (unsigned short*)alloc((size_t)N * 128 * 2);
    unsigned short* Wa1 = (unsigned short*)alloc(16 * 128 * 2);
    unsigned short* Wa2 = (unsigned short*)alloc(16 * 64 * 2);
    unsigned short* Wa3 = (unsigned short*)alloc(16 * 64 * 2);
    unsigned short* Wc1 = (unsigned short*)alloc((size_t)64 * 512 * 2);
    unsigned short* Wc2 = (unsigned short*)alloc((size_t)64 * 256 * 2);
    unsigned short* Wc3 = (unsigned short*)alloc((size_t)48 * 256 * 2);
    float* eav     = (float*)alloc((size_t)N * 8 * 4);
    float* edv     = (float*)alloc((size_t)N * 8 * 4);
    unsigned short* g   = (unsigned short*)alloc((size_t)N * 512 * 2);
    unsigned short* h1  = (unsigned short*)alloc((size_t)N * 64 * 2);
    unsigned short* h2  = (unsigned short*)alloc((size_t)N * 64 * 2);
    (void)ws_size;

    const void* eraw = d_in[1];

    const int X4 = N * 128 / 4;
    const int prepTotal = X4 + 16*128 + 16*64 + 16*64 + 64*512 + 64*256 + 48*256;
    const int prepBlocks = (prepTotal + 255) / 256;
    const int nbin = 64;
    const int chunkE = (E + nbin - 1) / nbin;
    const int mBlocks = (N + 63) / 64;         // 782
    const int nodeBlocks = N / 4;              // 12500

    // dispatch 1: prep ∪ bincount (no intra-dispatch dependencies)
    prep_hist_kernel<<<prepBlocks + 64, 256, 0, stream>>>(
        (const unsigned long long*)eraw, flag, x, xbf, X4,
        W1, as1, ad1, W2, as2, ad2, W3, as3, ad3,
        Wa1, Wa2, Wa3, Wc1, Wc2, Wc3,
        blkcnt, E, nbin, chunkE, prepBlocks);

    // dispatch 2: exclusive scan (own dispatch: boundary = ordering + coherence)
    binscan_kernel<<<1, 256, 0, stream>>>(blkcnt, NBUCKET * nbin);

    // dispatch 3: binscatter ∪ agemm (layer-1 alpha)
    scat_agemm_kernel<<<64 + mBlocks, 256, 0, stream>>>(
        eraw, flag, blkcnt, ebuf, E, nbin, chunkE, xbf, Wa1, eav, edv, N);

    // dispatch 4: per-bucket CSR finalize
    bfinal_kernel<<<NBUCKET, 256, 0, stream>>>(ebuf, blkcnt, row_ptr, colv, N, E, nbin);

    // layer 1: gather raw x (K=128); alpha for layer 2 fused into pgemm1
    gatherg_kernel<128><<<nodeBlocks, 256, 0, stream>>>(xbf, row_ptr, colv, eav, edv, g);
    pgemm_kernel<512, 64, false, true><<<mBlocks, 256, 0, stream>>>(g, Wc1, b1, h1, Wa2, eav, edv, N);

    // layer 2: features h1 (K=64); alpha for layer 3 fused into pgemm2
    gatherg_kernel<64><<<nodeBlocks, 256, 0, stream>>>(h1, row_ptr, colv, eav, edv, g);
    pgemm_kernel<256, 64, false, true><<<mBlocks, 256, 0, stream>>>(g, Wc2, b2, h2, Wa3, eav, edv, N);

    // layer 3: features h2 (K=64) + fused log_softmax
    gatherg_kernel<64><<<nodeBlocks, 256, 0, stream>>>(h2, row_ptr, colv, eav, edv, g);
    pgemm_kernel<256, 40, true, false><<<mBlocks, 256, 0, stream>>>(g, Wc3, b3, d_out, nullptr, nullptr, nullptr, N);
}

// Round 14
// 406.958 us; speedup vs baseline: 1.0302x; 1.0302x over previous
//
#include <hip/hip_runtime.h>
#include <math.h>

#define NNODES 50000
#define NEG_SLOPE 0.2f
#define NBUCKET 391          // buckets of 128 nodes; s fits 16 bits (N < 65536)
#define NBIN_MAX 128

typedef unsigned short ushort8v __attribute__((ext_vector_type(8)));
typedef unsigned short ushort4v __attribute__((ext_vector_type(4)));
typedef short short8v __attribute__((ext_vector_type(8)));
typedef float f32x4 __attribute__((ext_vector_type(4)));
typedef float f32x2 __attribute__((ext_vector_type(2)));

__device__ __forceinline__ unsigned short f2bf(float f){
    unsigned u = __float_as_uint(f);
    u += 0x7fff + ((u >> 16) & 1);   // RNE; inputs finite
    return (unsigned short)(u >> 16);
}

// ---------------- prep helpers ----------------
__device__ __forceinline__ void emit_wa(const float* __restrict__ W, const float* __restrict__ a_s,
                                        const float* __restrict__ a_d, unsigned short* __restrict__ Wt,
                                        int Kin, int C, int id){
    const int n = id / Kin, k = id - n * Kin;
    float v = 0.f;
    if(n < 8){
        const int hh = n & 3;
        const float* av = (n < 4) ? a_s : a_d;
        for(int c = 0; c < C; c++) v += W[(size_t)k * (4 * C) + hh * C + c] * av[hh * C + c];
    }
    Wt[id] = f2bf(v);
}

__device__ __forceinline__ void emit_wc(const float* __restrict__ W, unsigned short* __restrict__ Wt,
                                        int Kin, int C, int id){
    const int c = id / (4 * Kin);
    const int hk = id - c * (4 * Kin);
    const int h = hk / Kin, k = hk - h * Kin;
    const float v = (c < C) ? W[(size_t)k * (4 * C) + h * C + c] * 0.25f : 0.f;
    Wt[id] = f2bf(v);
}

// ---------------- dispatch 1: prep ∪ bincount ----------------
// Blocks [0, prepBlocks): flag detect (block 0) + xbf + Wa* + Wc*.
// Blocks [prepBlocks, prepBlocks+64): per-block LDS bucket histogram of a 1/64 edge
// chunk; flag recomputed locally via per-wave ballot (no cross-block dependency).
__global__ __launch_bounds__(256) void prep_hist_kernel(
        const unsigned long long* __restrict__ e, int* __restrict__ flag,
        const float* __restrict__ x, unsigned short* __restrict__ xbf, int X4,
        const float* __restrict__ W1, const float* __restrict__ as1, const float* __restrict__ ad1,
        const float* __restrict__ W2, const float* __restrict__ as2, const float* __restrict__ ad2,
        const float* __restrict__ W3, const float* __restrict__ as3, const float* __restrict__ ad3,
        unsigned short* __restrict__ Wa1, unsigned short* __restrict__ Wa2,
        unsigned short* __restrict__ Wa3, unsigned short* __restrict__ Wc1,
        unsigned short* __restrict__ Wc2, unsigned short* __restrict__ Wc3,
        int* __restrict__ blkcnt,
        int E, int nbin, int chunk, int prepBlocks){
    __shared__ int lcnt[NBUCKET];
    const int t = threadIdx.x;

    if((int)blockIdx.x < prepBlocks){
        if(blockIdx.x == 0 && t < 64){
            const unsigned long long v = e[t];
            const unsigned long long mask = __ballot(v >= (1ULL << 32));
            if(t == 0) *flag = (mask == 0ULL) ? 1 : 0;
        }
        int id = blockIdx.x * 256 + t;
        if(id < X4){
            const float4 v = *(const float4*)&x[(size_t)id * 4];
            ushort4v o;
            o[0] = f2bf(v.x); o[1] = f2bf(v.y); o[2] = f2bf(v.z); o[3] = f2bf(v.w);
            *(ushort4v*)&xbf[(size_t)id * 4] = o;
            return;
        }
        id -= X4;
        if(id < 16 * 128){ emit_wa(W1, as1, ad1, Wa1, 128, 64, id); return; }
        id -= 16 * 128;
        if(id < 16 * 64){ emit_wa(W2, as2, ad2, Wa2, 64, 64, id); return; }
        id -= 16 * 64;
        if(id < 16 * 64){ emit_wa(W3, as3, ad3, Wa3, 64, 40, id); return; }
        id -= 16 * 64;
        if(id < 64 * 512){ emit_wc(W1, Wc1, 128, 64, id); return; }
        id -= 64 * 512;
        if(id < 64 * 256){ emit_wc(W2, Wc2, 64, 64, id); return; }
        id -= 64 * 256;
        if(id < 48 * 256){ emit_wc(W3, Wc3, 64, 40, id); }
        return;
    }

    // ---- bincount block ----
    const int bb = blockIdx.x - prepBlocks;       // 0..63
    for(int i = t; i < NBUCKET; i += 256) lcnt[i] = 0;
    // local flag: lanes of each wave read e[0..63], per-wave ballot (block-uniform)
    const unsigned long long v = e[t & 63];
    const unsigned long long mask = __ballot(v >= (1ULL << 32));
    const bool f = (mask == 0ULL);
    __syncthreads();
    const int beg = bb * chunk, end = min(beg + chunk, E);
    for(int i = beg + t; i < end; i += 256){
        const int d = f ? (int)((const long long*)e)[E + i] : ((const int*)e)[E + i];
        atomicAdd(&lcnt[d >> 7], 1);              // LDS atomic only
    }
    __syncthreads();
    for(int b = t; b < NBUCKET; b += 256) blkcnt[b * nbin + bb] = lcnt[b];
}

// ---------------- in-place exclusive scan of blkcnt[0..total) (single block) ----------
__global__ __launch_bounds__(256) void binscan_kernel(int* __restrict__ blkcnt, int total){
    __shared__ int part[256];
    const int t = threadIdx.x;
    const int per = (total + 255) / 256;
    const int beg = t * per, end = min(beg + per, total);
    int sum = 0;
    for(int i = beg; i < end; i++) sum += blkcnt[i];
    part[t] = sum;
    __syncthreads();
    for(int off = 1; off < 256; off <<= 1){
        const int add = (t >= off) ? part[t - off] : 0;
        __syncthreads();
        part[t] += add;
        __syncthreads();
    }
    int run = part[t] - sum;
    for(int i = beg; i < end; i++){
        const int v = blkcnt[i];
        blkcnt[i] = run;
        run += v;
    }
}

// ---------------- dispatch 3: binscatter ∪ agemm (layer-1 alpha) ----------------
__global__ __launch_bounds__(256) void scat_agemm_kernel(
        const void* __restrict__ e, const int* __restrict__ flag,
        const int* __restrict__ blkcnt, unsigned* __restrict__ ebuf,
        int E, int nbin, int chunk,
        const unsigned short* __restrict__ A, const unsigned short* __restrict__ Wa,
        float* __restrict__ ea, float* __restrict__ ed, int M){
    __shared__ int lcur[NBUCKET];
    const int t = threadIdx.x;
    if((int)blockIdx.x < 64){
        const int blk = blockIdx.x;
        for(int b = t; b < NBUCKET; b += 256) lcur[b] = blkcnt[b * nbin + blk];
        __syncthreads();
        const bool f = (*flag) != 0;
        const int beg = blk * chunk;
        const int end = min(beg + chunk, E);
        for(int i = beg + t; i < end; i += 256){
            int s, d;
            if(f){ s = (int)((const long long*)e)[i]; d = (int)((const long long*)e)[E + i]; }
            else { s = ((const int*)e)[i];            d = ((const int*)e)[E + i]; }
            const int b = d >> 7;
            const int p = atomicAdd(&lcur[b], 1);
            ebuf[p] = (unsigned)s | ((unsigned)(d & 127) << 16) | ((unsigned)b << 23);
        }
        return;
    }
    // ---- agemm<128> block ----
    constexpr int K = 128;
    const int lane = t & 63;
    const int wave = t >> 6;
    const int quad = lane >> 4;
    const int l16 = lane & 15;
    const int bm = ((int)blockIdx.x - 64) * 64;
    const int m = min(bm + wave * 16 + l16, M - 1);
    f32x4 acc = {0,0,0,0};
    #pragma unroll
    for(int k0 = 0; k0 < K; k0 += 32){
        const short8v a = *(const short8v*)&A[(size_t)m * K + k0 + quad * 8];
        const short8v b = *(const short8v*)&Wa[(size_t)l16 * K + k0 + quad * 8];
        acc = __builtin_amdgcn_mfma_f32_16x16x32_bf16(a, b, acc, 0, 0, 0);
    }
    if(l16 < 8){
        const int h = l16 & 3;
        float* dst = (l16 < 4) ? ea : ed;
        const int rbase = bm + wave * 16 + quad * 4;
        #pragma unroll
        for(int r = 0; r < 4; r++){
            const int row = rbase + r;
            if(row < M){
                const float v = acc[r];
                *(f32x2*)&dst[(size_t)row * 8 + 2 * h] = (f32x2){__expf(v), __expf(NEG_SLOPE * v)};
            }
        }
    }
}

// ---------------- per-bucket finalize: local hist + scan -> row_ptr; local scatter -> col
__global__ __launch_bounds__(256) void bfinal_kernel(const unsigned* __restrict__ ebuf,
                                                     const int* __restrict__ blkcnt,
                                                     int* __restrict__ row_ptr, int* __restrict__ col,
                                                     int N, int E, int nbin){
    __shared__ int lcnt[128], lcur[128], sh[128];
    const int b = blockIdx.x;
    const int t = threadIdx.x;
    const int nlo = b << 7;
    const int base = blkcnt[b * nbin];
    const int next = (b == NBUCKET - 1) ? E : blkcnt[(b + 1) * nbin];
    const int cnt = next - base;
    if(t < 128) lcnt[t] = 0;
    __syncthreads();
    for(int i = t; i < cnt; i += 256) atomicAdd(&lcnt[(ebuf[base + i] >> 16) & 127], 1);
    __syncthreads();
    if(t < 128) sh[t] = lcnt[t];
    __syncthreads();
    for(int off = 1; off < 128; off <<= 1){
        const int add = (t >= off && t < 128) ? sh[t - off] : 0;
        __syncthreads();
        if(t < 128) sh[t] += add;
        __syncthreads();
    }
    if(t < 128){
        const int excl = sh[t] - lcnt[t];
        lcur[t] = excl;
        if(nlo + t < N) row_ptr[nlo + t] = base + excl;
    }
    if(b == 0 && t == 0) row_ptr[N] = E;
    __syncthreads();
    for(int i = t; i < cnt; i += 256){
        const unsigned w = ebuf[base + i];
        const int p = atomicAdd(&lcur[(w >> 16) & 127], 1);
        col[base + p] = (int)(w & 0xffffu);
    }
}

// ---------------- edge-parallel RAW gather (round-6/11 proven shape, verbatim) -------
// g[n][h][K] = (sum_e w_h * X[s]) / dnm_h. Block 256 = 4 waves, 1 node/wave,
// dynamic 12500-block dispatch (HW load-balancing). This shape is a measured
// local optimum: coarser waves (r2), wider lanes (r9), persistent grid (r12),
// and deeper unroll (r13) all regressed.
template<int K>
__global__ __launch_bounds__(256) void gatherg_kernel(const unsigned short* __restrict__ X,
                                                      const int* __restrict__ row_ptr,
                                                      const int* __restrict__ col,
                                                      const float* __restrict__ ea,
                                                      const float* __restrict__ ed,
                                                      unsigned short* __restrict__ g){
    __shared__ int   ls[4][64];
    __shared__ float lw[4][64][4];
    const int lane = threadIdx.x & 63;
    const int wave = threadIdx.x >> 6;
    const int n    = blockIdx.x * 4 + wave;
    const int rs = row_ptr[n], re = row_ptr[n + 1];
    const int T = re - rs + 1;                    // edges + virtual self loop
    const float4 edA = *(const float4*)&ed[(size_t)n * 8];
    const float4 edB = *(const float4*)&ed[(size_t)n * 8 + 4];

    f32x2 acc[4];
    #pragma unroll
    for(int h = 0; h < 4; h++) acc[h] = (f32x2){0.f, 0.f};
    float d0 = 0.f, d1 = 0.f, d2 = 0.f, d3 = 0.f;

    const int c2 = (K == 128) ? (lane * 2) : ((lane & 31) * 2);
    const int eo = lane >> 5;

    for(int base = 0; base < T; base += 64){
        const int ecnt = min(T - base, 64);
        if(lane < ecnt){
            const int e = rs + base + lane;
            const int s = (e < re) ? col[e] : n;  // e==re => self loop
            const float4 eaA = *(const float4*)&ea[(size_t)s * 8];
            const float4 eaB = *(const float4*)&ea[(size_t)s * 8 + 4];
            const float w0 = fmaxf(eaA.x * edA.x, eaA.y * edA.y);
            const float w1 = fmaxf(eaA.z * edA.z, eaA.w * edA.w);
            const float w2 = fmaxf(eaB.x * edB.x, eaB.y * edB.y);
            const float w3 = fmaxf(eaB.z * edB.z, eaB.w * edB.w);
            d0 += w0; d1 += w1; d2 += w2; d3 += w3;
            ls[wave][lane] = s;
            *(f32x4*)&lw[wave][lane][0] = (f32x4){w0, w1, w2, w3};
        }
        if constexpr(K == 128){
            auto body = [&](int e){
                const int s = ls[wave][e];                      // LDS broadcast
                const f32x4 w4 = *(const f32x4*)&lw[wave][e][0];
                const unsigned u = *(const unsigned*)&X[(size_t)s * K + c2];
                const f32x2 v = {__uint_as_float(u << 16), __uint_as_float(u & 0xffff0000u)};
                acc[0] += (f32x2){w4[0], w4[0]} * v;
                acc[1] += (f32x2){w4[1], w4[1]} * v;
                acc[2] += (f32x2){w4[2], w4[2]} * v;
                acc[3] += (f32x2){w4[3], w4[3]} * v;
            };
            int e = 0;
            for(; e + 4 <= ecnt; e += 4){ body(e); body(e + 1); body(e + 2); body(e + 3); }
            for(; e < ecnt; e++) body(e);
        } else {
            auto body = [&](int p){                             // pair: edges p, p+1
                const int e = p + eo;
                if(e < ecnt){
                    const int s = ls[wave][e];                  // 2-way LDS (free)
                    const f32x4 w4 = *(const f32x4*)&lw[wave][e][0];
                    const unsigned u = *(const unsigned*)&X[(size_t)s * K + c2];
                    const f32x2 v = {__uint_as_float(u << 16), __uint_as_float(u & 0xffff0000u)};
                    acc[0] += (f32x2){w4[0], w4[0]} * v;
                    acc[1] += (f32x2){w4[1], w4[1]} * v;
                    acc[2] += (f32x2){w4[2], w4[2]} * v;
                    acc[3] += (f32x2){w4[3], w4[3]} * v;
                }
            };
            int p = 0;
            for(; p + 8 <= ecnt; p += 8){ body(p); body(p + 2); body(p + 4); body(p + 6); }
            for(; p < ecnt; p += 2) body(p);
        }
    }

    #pragma unroll
    for(int msk = 1; msk < 64; msk <<= 1){
        d0 += __shfl_xor(d0, msk); d1 += __shfl_xor(d1, msk);
        d2 += __shfl_xor(d2, msk); d3 += __shfl_xor(d3, msk);
    }
    if constexpr(K == 64){
        #pragma unroll
        for(int h = 0; h < 4; h++){
            acc[h][0] += __shfl_xor(acc[h][0], 32);
            acc[h][1] += __shfl_xor(acc[h][1], 32);
        }
    }
    const float invs[4] = {1.f / d0, 1.f / d1, 1.f / d2, 1.f / d3};
    if(K == 128 || lane < 32){
        #pragma unroll
        for(int h = 0; h < 4; h++){
            const unsigned lo = f2bf(acc[h][0] * invs[h]);
            const unsigned hi = f2bf(acc[h][1] * invs[h]);
            *(unsigned*)&g[(size_t)n * (4 * K) + h * K + c2] = lo | (hi << 16);
        }
    }
}

// ---------------- post-aggregation GEMM (+fused next-layer alpha) ----------------
template<int KC, int NC, bool FINAL, bool ALPHA>
__global__ __launch_bounds__(256) void pgemm_kernel(const unsigned short* __restrict__ A,
                                                    const unsigned short* __restrict__ Bt,
                                                    const float* __restrict__ bias,
                                                    void* __restrict__ outv,
                                                    const unsigned short* __restrict__ Wa,
                                                    float* __restrict__ ea,
                                                    float* __restrict__ ed,
                                                    int M){
    constexpr int NT = (NC + 15) / 16;   // 4 (NC=64) or 3 (NC=40)
    __shared__ unsigned short lh[ALPHA ? 4 : 1][16][72];   // 72-stride: 16B-aligned rows, 2-way banks
    const int lane = threadIdx.x & 63;
    const int wave = threadIdx.x >> 6;
    const int quad = lane >> 4;
    const int l16 = lane & 15;
    const int bm = blockIdx.x * 64;
    const int m = min(bm + wave * 16 + l16, M - 1);
    const size_t arow = (size_t)m * KC;

    f32x4 acc[NT];
    #pragma unroll
    for(int t = 0; t < NT; t++) acc[t] = (f32x4){0,0,0,0};

    for(int k0 = 0; k0 < KC; k0 += 32){
        const short8v a = *(const short8v*)&A[arow + k0 + quad * 8];
        #pragma unroll
        for(int t = 0; t < NT; t++){
            const short8v b = *(const short8v*)&Bt[(size_t)(t * 16 + l16) * KC + k0 + quad * 8];
            acc[t] = __builtin_amdgcn_mfma_f32_16x16x32_bf16(a, b, acc[t], 0, 0, 0);
        }
    }
    const int rbase = bm + wave * 16 + quad * 4;
    if(!FINAL){
        unsigned short* out = (unsigned short*)outv;
        #pragma unroll
        for(int t = 0; t < NT; t++){
            const int c = t * 16 + l16;
            #pragma unroll
            for(int r = 0; r < 4; r++){
                const unsigned short hb = f2bf(fmaxf(acc[t][r] + bias[c], 0.f));
                const int row = rbase + r;
                if(row < M) out[(size_t)row * NC + c] = hb;
                if constexpr(ALPHA) lh[wave][quad * 4 + r][c] = hb;
            }
        }
        if constexpr(ALPHA){
            // wave-private LDS tile: within-wave lgkmcnt ordering suffices (no barrier)
            f32x4 a4 = {0, 0, 0, 0};
            #pragma unroll
            for(int k0 = 0; k0 < 64; k0 += 32){
                const short8v a = *(const short8v*)&lh[wave][l16][k0 + quad * 8];
                const short8v b = *(const short8v*)&Wa[(size_t)l16 * 64 + k0 + quad * 8];
                a4 = __builtin_amdgcn_mfma_f32_16x16x32_bf16(a, b, a4, 0, 0, 0);
            }
            if(l16 < 8){
                const int h = l16 & 3;
                float* dst = (l16 < 4) ? ea : ed;
                #pragma unroll
                for(int r = 0; r < 4; r++){
                    const int row = rbase + r;
                    if(row < M){
                        const float v = a4[r];
                        *(f32x2*)&dst[(size_t)row * 8 + 2 * h] = (f32x2){__expf(v), __expf(NEG_SLOPE * v)};
                    }
                }
            }
        }
    } else {
        float* out = (float*)outv;
        float o[NT][4];
        #pragma unroll
        for(int t = 0; t < NT; t++){
            const int c = t * 16 + l16;
            const bool valid = c < 40;
            const float bc = valid ? bias[c] : 0.f;
            #pragma unroll
            for(int r = 0; r < 4; r++)
                o[t][r] = valid ? fmaxf(acc[t][r] + bc, 0.f) : -INFINITY;
        }
        #pragma unroll
        for(int r = 0; r < 4; r++){
            float mx = o[0][r];
            #pragma unroll
            for(int t = 1; t < NT; t++) mx = fmaxf(mx, o[t][r]);
            #pragma unroll
            for(int off = 1; off < 16; off <<= 1) mx = fmaxf(mx, __shfl_xor(mx, off));
            float se = 0.f;
            #pragma unroll
            for(int t = 0; t < NT; t++) se += (o[t][r] > -INFINITY) ? __expf(o[t][r] - mx) : 0.f;
            #pragma unroll
            for(int off = 1; off < 16; off <<= 1) se += __shfl_xor(se, off);
            const float lz = mx + logf(se);
            const int row = rbase + r;
            if(row < M){
                #pragma unroll
                for(int t = 0; t < NT; t++){
                    const int c = t * 16 + l16;
                    if(c < 40) out[(size_t)row * 40 + c] = o[t][r] - lz;
                }
            }
        }
    }
}

// ---------------- driver ----------------
extern "C" void kernel_launch(void* const* d_in, const int* in_sizes, int n_in,
                              void* d_out, int out_size, void* d_ws, size_t ws_size,
                              hipStream_t stream){
    const int N = NNODES;
    const int E = in_sizes[1] / 2;

    const float* x   = (const float*)d_in[0];
    const float* W1  = (const float*)d_in[2];
    const float* as1 = (const float*)d_in[3];
    const float* ad1 = (const float*)d_in[4];
    const float* b1  = (const float*)d_in[5];
    const float* W2  = (const float*)d_in[6];
    const float* as2 = (const float*)d_in[7];
    const float* ad2 = (const float*)d_in[8];
    const float* b2  = (const float*)d_in[9];
    const float* W3  = (const float*)d_in[10];
    const float* as3 = (const float*)d_in[11];
    const float* ad3 = (const float*)d_in[12];
    const float* b3  = (const float*)d_in[13];

    char* ws = (char*)d_ws;
    size_t off = 0;
    auto alloc = [&](size_t bytes) -> void* {
        void* p = ws + off;
        off = (off + bytes + 255) & ~(size_t)255;
        return p;
    };
    int*      flag    = (int*)     alloc(4);
    int*      row_ptr = (int*)     alloc((size_t)(N + 1) * 4);
    int*      colv    = (int*)     alloc((size_t)E * 4);
    int*      blkcnt  = (int*)     alloc((size_t)NBUCKET * NBIN_MAX * 4);
    unsigned* ebuf    = (unsigned*)alloc((size_t)E * 4);
    unsigned short* xbf = (unsigned short*)alloc((size_t)N * 128 * 2);
    unsigned short* Wa1 = (unsigned short*)alloc(16 * 128 * 2);
    unsigned short* Wa2 = (unsigned short*)alloc(16 * 64 * 2);
    unsigned short* Wa3 = (unsigned short*)alloc(16 * 64 * 2);
    unsigned short* Wc1 = (unsigned short*)alloc((size_t)64 * 512 * 2);
    unsigned short* Wc2 = (unsigned short*)alloc((size_t)64 * 256 * 2);
    unsigned short* Wc3 = (unsigned short*)alloc((size_t)48 * 256 * 2);
    float* eav     = (float*)alloc((size_t)N * 8 * 4);
    float* edv     = (float*)alloc((size_t)N * 8 * 4);
    unsigned short* g   = (unsigned short*)alloc((size_t)N * 512 * 2);
    unsigned short* h1  = (unsigned short*)alloc((size_t)N * 64 * 2);
    unsigned short* h2  = (unsigned short*)alloc((size_t)N * 64 * 2);
    (void)ws_size;

    const void* eraw = d_in[1];

    const int X4 = N * 128 / 4;
    const int prepTotal = X4 + 16*128 + 16*64 + 16*64 + 64*512 + 64*256 + 48*256;
    const int prepBlocks = (prepTotal + 255) / 256;
    const int nbin = 64;
    const int chunkE = (E + nbin - 1) / nbin;
    const int mBlocks = (N + 63) / 64;         // 782
    const int nodeBlocks = N / 4;              // 12500

    // dispatch 1: prep ∪ bincount (no intra-dispatch dependencies)
    prep_hist_kernel<<<prepBlocks + 64, 256, 0, stream>>>(
        (const unsigned long long*)eraw, flag, x, xbf, X4,
        W1, as1, ad1, W2, as2, ad2, W3, as3, ad3,
        Wa1, Wa2, Wa3, Wc1, Wc2, Wc3,
        blkcnt, E, nbin, chunkE, prepBlocks);

    // dispatch 2: exclusive scan (own dispatch: boundary = ordering + coherence)
    binscan_kernel<<<1, 256, 0, stream>>>(blkcnt, NBUCKET * nbin);

    // dispatch 3: binscatter ∪ agemm (layer-1 alpha)
    scat_agemm_kernel<<<64 + mBlocks, 256, 0, stream>>>(
        eraw, flag, blkcnt, ebuf, E, nbin, chunkE, xbf, Wa1, eav, edv, N);

    // dispatch 4: per-bucket CSR finalize
    bfinal_kernel<<<NBUCKET, 256, 0, stream>>>(ebuf, blkcnt, row_ptr, colv, N, E, nbin);

    // layer 1: gather raw x (K=128); alpha for layer 2 fused into pgemm1
    gatherg_kernel<128><<<nodeBlocks, 256, 0, stream>>>(xbf, row_ptr, colv, eav, edv, g);
    pgemm_kernel<512, 64, false, true><<<mBlocks, 256, 0, stream>>>(g, Wc1, b1, h1, Wa2, eav, edv, N);

    // layer 2: features h1 (K=64); alpha for layer 3 fused into pgemm2
    gatherg_kernel<64><<<nodeBlocks, 256, 0, stream>>>(h1, row_ptr, colv, eav, edv, g);
    pgemm_kernel<256, 64, false, true><<<mBlocks, 256, 0, stream>>>(g, Wc2, b2, h2, Wa3, eav, edv, N);

    // layer 3: features h2 (K=64) + fused log_softmax
    gatherg_kernel<64><<<nodeBlocks, 256, 0, stream>>>(h2, row_ptr, colv, eav, edv, g);
    pgemm_kernel<256, 40, true, false><<<mBlocks, 256, 0, stream>>>(g, Wc3, b3, d_out, nullptr, nullptr, nullptr, N);
}